// Round 10
// baseline (230.015 us; speedup 1.0000x reference)
//
#include <hip/hip_runtime.h>

#define N_NODES 25600
#define F_IN 400
#define NE 512000
#define NB 64
#define NPG 400
#define EPG 8000
#define BN_EPS 1e-5f
#define NBLK 256
#define SM_SIZE 137216

typedef __attribute__((ext_vector_type(8))) short short8;
typedef __attribute__((ext_vector_type(4))) float floatx4;
typedef unsigned short us;
typedef unsigned long long u64;

__device__ __forceinline__ unsigned short f2bf(float f) {
    unsigned int u = __float_as_uint(f);
    u += 0x7FFF + ((u >> 16) & 1);   // RNE
    return (unsigned short)(u >> 16);
}
__device__ __forceinline__ float bf2f(unsigned short s) {
    return __uint_as_float((unsigned int)s << 16);
}
// packed f32x2 -> bf16x2 (RNE), lo in low half
__device__ __forceinline__ unsigned cvtpk(float lo, float hi) {
    unsigned r;
    asm("v_cvt_pk_bf16_f32 %0, %1, %2" : "=v"(r) : "v"(lo), "v"(hi));
    return r;
}
// agent-scope (coherence-point) store: lands at L3, bypassing the writer's non-coherent L2.
__device__ __forceinline__ void ast64(void* p, u64 v) {
    __hip_atomic_store((u64*)p, v, __ATOMIC_RELAXED, __HIP_MEMORY_SCOPE_AGENT);
}
__device__ __forceinline__ u64 pk4(unsigned short a, unsigned short b, unsigned short c, unsigned short d) {
    return (u64)a | ((u64)b << 16) | ((u64)c << 32) | ((u64)d << 48);
}

// ---- hierarchical grid barrier: 16 leaves x 16 blocks + root ----
__device__ __forceinline__ void gsync_tree(unsigned* bar, int bid, int phase) {
    __syncthreads();                       // drains vmcnt: prior stores/atomics complete
    if (threadIdx.x == 0) {
        unsigned* leaf = bar + 32 + (bid >> 4) * 32;        // 128B-spaced lines
        unsigned v = __hip_atomic_fetch_add(leaf, 1u, __ATOMIC_RELAXED, __HIP_MEMORY_SCOPE_AGENT);
        if (v == (unsigned)(phase * 16 - 1))
            __hip_atomic_fetch_add(bar, 1u, __ATOMIC_RELAXED, __HIP_MEMORY_SCOPE_AGENT);
        while (__hip_atomic_load(bar, __ATOMIC_RELAXED, __HIP_MEMORY_SCOPE_AGENT) < (unsigned)(phase * 16))
            __builtin_amdgcn_s_sleep(8);
        asm volatile("" ::: "memory");
    }
    __syncthreads();
}

// ---- per-graph micro-barrier: only the 4 blocks of one graph ----
__device__ __forceinline__ void gbar4(unsigned* gc, int stage) {
    __syncthreads();
    if (threadIdx.x == 0) {
        __hip_atomic_fetch_add(gc, 1u, __ATOMIC_RELAXED, __HIP_MEMORY_SCOPE_AGENT);
        while (__hip_atomic_load(gc, __ATOMIC_RELAXED, __HIP_MEMORY_SCOPE_AGENT) < (unsigned)(stage * 4))
            __builtin_amdgcn_s_sleep(8);
        asm volatile("" ::: "memory");
    }
    __syncthreads();
}

// LDS plan (137216 B static, 1 block/CU):
//  prep : cnt 44800 @0
//  embed: Bf[128][456] @0 (116736) | As[128][72] @116736 (18432) | Wex @135168 (2048)
//  agg  : Bf @0 ; epilogue zl[128][136] @0 ; rs @116736 / rq @118784
//  post : zl @0 | coefs @34816 | Bw[128][136] @35840 (ends 105472)
//  tail : red @0 ; head pl/o0/o1 @0

// ---------------- prep: u8 adjacency slab (block-private) + balanced weight-panel jobs ----------------

__device__ __forceinline__ void ph_prep(unsigned char* sm, int g, int q, int bid, int tid,
        const int* __restrict__ src, const int* __restrict__ dst, unsigned char* __restrict__ Sb8,
        const float* __restrict__ wa0, const float* __restrict__ wa1, const float* __restrict__ wa2,
        const float* __restrict__ wb0, const float* __restrict__ wb1, const float* __restrict__ wb2,
        us* __restrict__ wt0, us* __restrict__ wtb0, us* __restrict__ wta1,
        us* __restrict__ wtb1, us* __restrict__ wta2, us* __restrict__ wtb2) {
    int r0 = q * 112;
    int* cnt = (int*)sm;                      // 112*400 u8 counts packed in ints
    for (int i = tid; i < 11200; i += 1024) cnt[i] = 0;
    __syncthreads();
    int ebase = g * EPG, nbase = g * NPG;
    for (int e = tid; e < EPG; e += 1024) {
        int d = dst[ebase + e] - nbase;
        int dr = d - r0;
        if ((unsigned)dr < 112u) {
            int s = src[ebase + e] - nbase;
            int idx = dr * NPG + s;
            atomicAdd(&cnt[idx >> 2], (int)(1u << ((idx & 3) * 8)));
        }
    }
    __syncthreads();
    const unsigned char* cb = (const unsigned char*)cnt;
    // u8 slab rows [r0, r0+112), cols 0..447 (cols>=400 zero); block-private plain stores
    for (int i = tid; i < 112 * 56; i += 1024) {
        int rr = i / 56, c8 = (i % 56) * 8;
        int R = r0 + rr;
        u64 pk = 0;
#pragma unroll
        for (int j = 0; j < 8; ++j) {
            int c = c8 + j;
            unsigned v = (R < NPG && c < NPG) ? (unsigned)cb[rr * NPG + c] + (c == R ? 1u : 0u) : 0u;
            pk |= (u64)(v & 255u) << (8 * j);
        }
        *(u64*)&Sb8[((size_t)g * 448 + R) * 448 + c8] = pk;
    }
    // balanced one-shot jobs: 34816 u64 slots / 256 blocks = 136 each
    if (tid < 136) {
        int idx = bid * 136 + tid;
        if (idx < 14336) {                   // wt0: [n=128][k=448] bf16, zero-padded K
            int n = idx / 112, k0 = (idx % 112) * 4;
            unsigned short o[4];
#pragma unroll
            for (int j = 0; j < 4; ++j) {
                int k = k0 + j;
                o[j] = (k < 400) ? f2bf(wa0[(size_t)k * 128 + n]) : (unsigned short)0;
            }
            ast64(&wt0[(size_t)n * 448 + k0], pk4(o[0], o[1], o[2], o[3]));
        } else {                             // 5 x [n=128][k=128] transposes
            int r2 = idx - 14336;            // 0..20479
            int m = r2 >> 12, q2 = r2 & 4095;
            int n = q2 >> 5, k0 = (q2 & 31) * 4;
            const float* smat = (m == 0) ? wb0 : (m == 1) ? wa1 : (m == 2) ? wb1 : (m == 3) ? wa2 : wb2;
            us* dmat = (m == 0) ? wtb0 : (m == 1) ? wta1 : (m == 2) ? wtb1 : (m == 3) ? wta2 : wtb2;
            unsigned short o[4];
#pragma unroll
            for (int j = 0; j < 4; ++j) o[j] = f2bf(smat[(size_t)(k0 + j) * 128 + n]);
            ast64(&dmat[(size_t)n * 128 + k0], pk4(o[0], o[1], o[2], o[3]));
        }
    }
}

// ---------------- embed: tT0 = ([x | ge | he] @ W0a)^T ----------------

__device__ __forceinline__ void ph_embed(unsigned char* sm, int g, int q, int tid,
        const float* __restrict__ x, const us* __restrict__ wt0, const float* __restrict__ wa0,
        const int* __restrict__ gid, const float* __restrict__ ge, const float* __restrict__ he,
        us* __restrict__ tT0) {
    us (*Bf)[456] = (us(*)[456])sm;
    us (*As)[72] = (us(*)[72])(sm + 116736);
    float (*Wex)[128] = (float(*)[128])(sm + 135168);
    int nb = g * NPG + q * 100;
    int wave = tid >> 6, lane = tid & 63;
    int wrow = wave >> 2, wc4 = wave & 3;
    int fm = lane & 15, quad = lane >> 4;

    // stage full W0^T panel: issue ALL loads, then all LDS writes (7x MLP)
    {
        short8 tp[7];
#pragma unroll
        for (int j = 0; j < 7; ++j) {
            int i = tid + j * 1024;
            int col = i / 56, kq = (i - col * 56) * 8;
            tp[j] = *(const short8*)(wt0 + (size_t)col * 448 + kq);
        }
#pragma unroll
        for (int j = 0; j < 7; ++j) {
            int i = tid + j * 1024;
            int col = i / 56, kq = (i - col * 56) * 8;
            *(short8*)&Bf[col][kq] = tp[j];
        }
    }
    for (int i = tid; i < 512; i += 1024)
        Wex[i >> 7][i & 127] = wa0[(size_t)(400 + (i >> 7)) * 128 + (i & 127)];

    floatx4 acc[2][2];
#pragma unroll
    for (int rt = 0; rt < 2; ++rt)
#pragma unroll
        for (int ct = 0; ct < 2; ++ct) acc[rt][ct] = (floatx4){0.f, 0.f, 0.f, 0.f};

    const int rA = tid >> 3, kcA = (tid & 7) * 8;
    float v[8];
    auto loadK = [&](int ks) {
        int kg = ks * 64 + kcA;
        if (rA < 100) {
            const float* ar = x + (size_t)(nb + rA) * F_IN;
            if (kg + 7 < 400) {
                float4 a = *(const float4*)(ar + kg);
                float4 b = *(const float4*)(ar + kg + 4);
                v[0] = a.x; v[1] = a.y; v[2] = a.z; v[3] = a.w;
                v[4] = b.x; v[5] = b.y; v[6] = b.z; v[7] = b.w;
            } else {
#pragma unroll
                for (int j = 0; j < 8; ++j) v[j] = (kg + j < 400) ? ar[kg + j] : 0.f;
            }
        } else {
#pragma unroll
            for (int j = 0; j < 8; ++j) v[j] = 0.f;
        }
    };

    loadK(0);
    for (int ks = 0; ks < 7; ++ks) {
        {
            union { unsigned w[4]; short8 s; } u;
            u.w[0] = cvtpk(v[0], v[1]);
            u.w[1] = cvtpk(v[2], v[3]);
            u.w[2] = cvtpk(v[4], v[5]);
            u.w[3] = cvtpk(v[6], v[7]);
            *(short8*)&As[rA][kcA] = u.s;
        }
        __syncthreads();            // first iter also covers Bf/Wex staging
        if (ks + 1 < 7) loadK(ks + 1);
#pragma unroll
        for (int k0l = 0; k0l < 64; k0l += 32) {
            short8 af[2], bf[2];
#pragma unroll
            for (int rt = 0; rt < 2; ++rt)
                af[rt] = *(const short8*)&As[wrow * 32 + rt * 16 + fm][k0l + quad * 8];
#pragma unroll
            for (int ct = 0; ct < 2; ++ct)
                bf[ct] = *(const short8*)&Bf[wc4 * 32 + ct * 16 + fm][ks * 64 + k0l + quad * 8];
#pragma unroll
            for (int rt = 0; rt < 2; ++rt)
#pragma unroll
                for (int ct = 0; ct < 2; ++ct)
                    acc[rt][ct] = __builtin_amdgcn_mfma_f32_16x16x32_bf16(
                        af[rt], bf[ct], acc[rt][ct], 0, 0, 0);
        }
        __syncthreads();
    }

#pragma unroll
    for (int rt = 0; rt < 2; ++rt)
#pragma unroll
        for (int ct = 0; ct < 2; ++ct) {
            int col = wc4 * 32 + ct * 16 + fm;
            int rl0 = wrow * 32 + rt * 16 + quad * 4;
            if (rl0 < 100) {
                float vv[4];
#pragma unroll
                for (int r = 0; r < 4; ++r) {
                    int row = nb + rl0 + r;
                    int gv = gid[row];
                    vv[r] = acc[rt][ct][r]
                          + ge[gv * 2] * Wex[0][col] + ge[gv * 2 + 1] * Wex[1][col]
                          + he[(row & 1) * 2] * Wex[2][col] + he[(row & 1) * 2 + 1] * Wex[3][col];
                }
                unsigned wlo = cvtpk(vv[0], vv[1]), whi = cvtpk(vv[2], vv[3]);
                ast64(&tT0[(size_t)col * N_NODES + nb + rl0], (u64)wlo | ((u64)whi << 32));
            }
        }
}

// ---------------- agg: z = (S+I)@t + ba ; A fragments direct from L1/L2-resident u8 slab ----------------

__device__ __forceinline__ void ph_agg(unsigned char* sm, int g, int q, int tid,
        const unsigned char* __restrict__ Sb8, const us* __restrict__ tTr, const float* __restrict__ ba,
        float* __restrict__ psum, float* __restrict__ psq, int bucket) {
    us (*Bf)[456] = (us(*)[456])sm;
    us (*zl)[136] = (us(*)[136])sm;
    float (*rs)[4][2][16] = (float(*)[4][2][16])(sm + 116736);
    float (*rq)[4][2][16] = (float(*)[4][2][16])(sm + 118784);
    int wave = tid >> 6, lane = tid & 63;
    int wrow = wave >> 2, wc4 = wave & 3;
    int fm = lane & 15, quad = lane >> 4;
    int node0 = g * NPG;

    // stage tT panel: ALL loads first (7x MLP), then LDS writes; k>=400 literal zeros
    {
        short8 tp[7];
        const short8 z8 = {0, 0, 0, 0, 0, 0, 0, 0};
#pragma unroll
        for (int j = 0; j < 7; ++j) {
            int i = tid + j * 1024;
            int col = i / 56, kq = (i - col * 56) * 8;
            tp[j] = (kq < 400) ? *(const short8*)(tTr + (size_t)col * N_NODES + node0 + kq) : z8;
        }
#pragma unroll
        for (int j = 0; j < 7; ++j) {
            int i = tid + j * 1024;
            int col = i / 56, kq = (i - col * 56) * 8;
            *(short8*)&Bf[col][kq] = tp[j];
        }
    }
    __syncthreads();

    floatx4 acc[2][2];
#pragma unroll
    for (int rt = 0; rt < 2; ++rt)
#pragma unroll
        for (int ct = 0; ct < 2; ++ct) acc[rt][ct] = (floatx4){0.f, 0.f, 0.f, 0.f};

    const unsigned char* a8 = Sb8 + ((size_t)g * 448 + q * 112) * 448;
#pragma unroll
    for (int ks = 0; ks < 7; ++ks) {
#pragma unroll
        for (int k0l = 0; k0l < 64; k0l += 32) {
            short8 af[2], bf[2];
#pragma unroll
            for (int rt = 0; rt < 2; ++rt) {
                if (wrow == 3 && rt == 1) {          // rows 112..127: beyond this block's 112 rows
                    af[rt] = (short8){0, 0, 0, 0, 0, 0, 0, 0};
                } else {
                    u64 v8 = *(const u64*)(a8 + (size_t)(wrow * 32 + rt * 16 + fm) * 448
                                           + ks * 64 + k0l + quad * 8);
                    unsigned lo = (unsigned)v8, hi = (unsigned)(v8 >> 32);
                    float f0 = (float)(lo & 255u), f1 = (float)((lo >> 8) & 255u);
                    float f2 = (float)((lo >> 16) & 255u), f3 = (float)(lo >> 24);
                    float f4 = (float)(hi & 255u), f5 = (float)((hi >> 8) & 255u);
                    float f6 = (float)((hi >> 16) & 255u), f7 = (float)(hi >> 24);
                    union { unsigned w[4]; short8 s; } u;
                    // bf16 truncation exact for ints <= 255
                    u.w[0] = __builtin_amdgcn_perm(__float_as_uint(f1), __float_as_uint(f0), 0x07060302u);
                    u.w[1] = __builtin_amdgcn_perm(__float_as_uint(f3), __float_as_uint(f2), 0x07060302u);
                    u.w[2] = __builtin_amdgcn_perm(__float_as_uint(f5), __float_as_uint(f4), 0x07060302u);
                    u.w[3] = __builtin_amdgcn_perm(__float_as_uint(f7), __float_as_uint(f6), 0x07060302u);
                    af[rt] = u.s;
                }
            }
#pragma unroll
            for (int ct = 0; ct < 2; ++ct)
                bf[ct] = *(const short8*)&Bf[wc4 * 32 + ct * 16 + fm][ks * 64 + k0l + quad * 8];
#pragma unroll
            for (int rt = 0; rt < 2; ++rt)
#pragma unroll
                for (int ct = 0; ct < 2; ++ct)
                    acc[rt][ct] = __builtin_amdgcn_mfma_f32_16x16x32_bf16(
                        af[rt], bf[ct], acc[rt][ct], 0, 0, 0);
        }
    }
    __syncthreads();   // B panel dead; zl overlays it

    int nrows = (q < 3) ? 112 : 64;
    float sc[2] = {0.f, 0.f}, sq2[2] = {0.f, 0.f};
#pragma unroll
    for (int rt = 0; rt < 2; ++rt)
#pragma unroll
        for (int ct = 0; ct < 2; ++ct) {
            int col = wc4 * 32 + ct * 16 + fm;
            int rl0 = wrow * 32 + rt * 16 + quad * 4;
            if (rl0 < nrows) {
                float bv = ba[col];
#pragma unroll
                for (int r = 0; r < 4; ++r) {
                    float vv = acc[rt][ct][r] + bv;
                    zl[rl0 + r][col] = f2bf(vv);
                    sc[ct] += vv;
                    sq2[ct] += vv * vv;
                }
            }
        }
#pragma unroll
    for (int ct = 0; ct < 2; ++ct) {
        sc[ct] += __shfl_xor(sc[ct], 16);
        sc[ct] += __shfl_xor(sc[ct], 32);
        sq2[ct] += __shfl_xor(sq2[ct], 16);
        sq2[ct] += __shfl_xor(sq2[ct], 32);
    }
    if (lane < 16) {
#pragma unroll
        for (int ct = 0; ct < 2; ++ct) { rs[wrow][wc4][ct][lane] = sc[ct]; rq[wrow][wc4][ct][lane] = sq2[ct]; }
    }
    __syncthreads();
    if (tid < 128) {
        int wc = tid >> 5, ct = (tid >> 4) & 1, f = tid & 15;
        float S = 0.f, Q = 0.f;
#pragma unroll
        for (int wr = 0; wr < 4; ++wr) { S += rs[wr][wc][ct][f]; Q += rq[wr][wc][ct][f]; }
        atomicAdd(&psum[bucket * 128 + tid], S);
        atomicAdd(&psq[bucket * 128 + tid], Q);
    }
}

// ---------------- post: BN + h=relu(relu(affine(z))@wb+bb) [+ t'=h@wa_next | pool] ----------------

template <int FINAL>
__device__ __forceinline__ void ph_post(unsigned char* sm, int g, int q, int tid,
        const float* __restrict__ psum, const float* __restrict__ psq,
        const float* __restrict__ gamma, const float* __restrict__ beta,
        const us* __restrict__ wtbP, const float* __restrict__ bb,
        const us* __restrict__ wanP, us* __restrict__ tTw, float& p0, float& p1) {
    us (*zl)[136] = (us(*)[136])sm;
    float* coefs = (float*)(sm + 34816);
    us (*Bw)[136] = (us(*)[136])(sm + 35840);
    int wave = tid >> 6, lane = tid & 63;
    int wrow = wave >> 2, wc4 = wave & 3;
    int fm = lane & 15, quad = lane >> 4;
    int nrows = (q < 3) ? 112 : 64;
    int nb = g * NPG + q * 112;

    // prefetch both weight panels (w2 held in registers across GEMM1)
    short8 w1[2], w2[2];
#pragma unroll
    for (int j = 0; j < 2; ++j) {
        int i = tid + j * 1024;
        int col = i >> 4, kq = (i & 15) * 8;
        w1[j] = *(const short8*)(wtbP + (size_t)col * 128 + kq);
        if (!FINAL) w2[j] = *(const short8*)(wanP + (size_t)col * 128 + kq);
    }

    if (tid < 128) {
        float S = 0.f, Q = 0.f;
#pragma unroll
        for (int b = 0; b < 16; ++b) {
            S += __hip_atomic_load(&psum[b * 128 + tid], __ATOMIC_RELAXED, __HIP_MEMORY_SCOPE_AGENT);
            Q += __hip_atomic_load(&psq[b * 128 + tid], __ATOMIC_RELAXED, __HIP_MEMORY_SCOPE_AGENT);
        }
        float invn = 1.0f / (float)N_NODES;
        float mu = S * invn;
        float var = Q * invn - mu * mu;
        float a = gamma[tid] * rsqrtf(var + BN_EPS);
        coefs[tid] = a;
        coefs[128 + tid] = beta[tid] - a * mu;
    }
#pragma unroll
    for (int j = 0; j < 2; ++j) {
        int i = tid + j * 1024;
        int col = i >> 4, kq = (i & 15) * 8;
        *(short8*)&Bw[col][kq] = w1[j];
    }
    __syncthreads();                 // coefs + Bw(wb^T) ready
    // affine + relu in place, pairwise
    for (int i = tid; i < 8192; i += 1024) {
        int rl = i >> 6, c2 = i & 63;
        unsigned* zw = (unsigned*)&zl[rl][0];
        unsigned w = zw[c2];
        int col = c2 * 2;
        float lo = fmaxf(coefs[col] * bf2f((us)(w & 0xffff)) + coefs[128 + col], 0.f);
        float hi = fmaxf(coefs[col + 1] * bf2f((us)(w >> 16)) + coefs[129 + col], 0.f);
        zw[c2] = cvtpk(lo, hi);
    }
    __syncthreads();                 // zl ready

    floatx4 acc[2][2];
#pragma unroll
    for (int rt = 0; rt < 2; ++rt)
#pragma unroll
        for (int ct = 0; ct < 2; ++ct) acc[rt][ct] = (floatx4){0.f, 0.f, 0.f, 0.f};

#pragma unroll
    for (int ks = 0; ks < 2; ++ks)
#pragma unroll
        for (int k0l = 0; k0l < 64; k0l += 32) {
            short8 af[2], bf[2];
#pragma unroll
            for (int rt = 0; rt < 2; ++rt)
                af[rt] = *(const short8*)&zl[wrow * 32 + rt * 16 + fm][ks * 64 + k0l + quad * 8];
#pragma unroll
            for (int ct = 0; ct < 2; ++ct)
                bf[ct] = *(const short8*)&Bw[wc4 * 32 + ct * 16 + fm][ks * 64 + k0l + quad * 8];
#pragma unroll
            for (int rt = 0; rt < 2; ++rt)
#pragma unroll
                for (int ct = 0; ct < 2; ++ct)
                    acc[rt][ct] = __builtin_amdgcn_mfma_f32_16x16x32_bf16(
                        af[rt], bf[ct], acc[rt][ct], 0, 0, 0);
        }

    if (FINAL) {
#pragma unroll
        for (int rt = 0; rt < 2; ++rt)
#pragma unroll
            for (int ct = 0; ct < 2; ++ct) {
                int col = wc4 * 32 + ct * 16 + fm;
                int rl0 = wrow * 32 + rt * 16 + quad * 4;
                if (rl0 < nrows) {
                    float bv = bb[col];
                    float s = 0.f;
#pragma unroll
                    for (int r = 0; r < 4; ++r) s += fmaxf(acc[rt][ct][r] + bv, 0.f);
                    if (ct == 0) p0 += s; else p1 += s;
                }
            }
        return;
    }

    __syncthreads();                 // all GEMM1 reads of zl and Bw done
    // h -> zl (in place); Bw <- wa_next^T (held registers)
#pragma unroll
    for (int rt = 0; rt < 2; ++rt)
#pragma unroll
        for (int ct = 0; ct < 2; ++ct) {
            int col = wc4 * 32 + ct * 16 + fm;
            float bv = bb[col];
            int rl0 = wrow * 32 + rt * 16 + quad * 4;
#pragma unroll
            for (int r = 0; r < 4; ++r)
                zl[rl0 + r][col] = f2bf(fmaxf(acc[rt][ct][r] + bv, 0.f));
        }
#pragma unroll
    for (int j = 0; j < 2; ++j) {
        int i = tid + j * 1024;
        int col = i >> 4, kq = (i & 15) * 8;
        *(short8*)&Bw[col][kq] = w2[j];
    }
    __syncthreads();

#pragma unroll
    for (int rt = 0; rt < 2; ++rt)
#pragma unroll
        for (int ct = 0; ct < 2; ++ct) acc[rt][ct] = (floatx4){0.f, 0.f, 0.f, 0.f};

#pragma unroll
    for (int ks = 0; ks < 2; ++ks)
#pragma unroll
        for (int k0l = 0; k0l < 64; k0l += 32) {
            short8 af[2], bf[2];
#pragma unroll
            for (int rt = 0; rt < 2; ++rt)
                af[rt] = *(const short8*)&zl[wrow * 32 + rt * 16 + fm][ks * 64 + k0l + quad * 8];
#pragma unroll
            for (int ct = 0; ct < 2; ++ct)
                bf[ct] = *(const short8*)&Bw[wc4 * 32 + ct * 16 + fm][ks * 64 + k0l + quad * 8];
#pragma unroll
            for (int rt = 0; rt < 2; ++rt)
#pragma unroll
                for (int ct = 0; ct < 2; ++ct)
                    acc[rt][ct] = __builtin_amdgcn_mfma_f32_16x16x32_bf16(
                        af[rt], bf[ct], acc[rt][ct], 0, 0, 0);
        }

#pragma unroll
    for (int rt = 0; rt < 2; ++rt)
#pragma unroll
        for (int ct = 0; ct < 2; ++ct) {
            int col = wc4 * 32 + ct * 16 + fm;
            int rl0 = wrow * 32 + rt * 16 + quad * 4;
            if (rl0 < nrows) {
                unsigned wlo = cvtpk(acc[rt][ct][0], acc[rt][ct][1]);
                unsigned whi = cvtpk(acc[rt][ct][2], acc[rt][ct][3]);
                ast64(&tTw[(size_t)col * N_NODES + nb + rl0], (u64)wlo | ((u64)whi << 32));
            }
        }
}

// ---------------- the single persistent kernel ----------------

__global__ __launch_bounds__(1024, 4) void persist_all(
        const float* __restrict__ x, const int* __restrict__ esrc, const int* __restrict__ edst,
        const int* __restrict__ gid, const float* __restrict__ ge, const float* __restrict__ he,
        const float* __restrict__ wa0, const float* __restrict__ ba0, const float* __restrict__ gg0,
        const float* __restrict__ be0, const float* __restrict__ wb0, const float* __restrict__ bbias0,
        const float* __restrict__ wa1, const float* __restrict__ ba1, const float* __restrict__ gg1,
        const float* __restrict__ be1, const float* __restrict__ wb1, const float* __restrict__ bbias1,
        const float* __restrict__ wa2, const float* __restrict__ ba2, const float* __restrict__ gg2,
        const float* __restrict__ be2, const float* __restrict__ wb2, const float* __restrict__ bbias2,
        const float* __restrict__ wfa, const float* __restrict__ bfa,
        const float* __restrict__ wfb, const float* __restrict__ bfb,
        us* __restrict__ tT0, us* __restrict__ tT1, us* __restrict__ tT2,
        unsigned char* __restrict__ Sb8, float* __restrict__ pstat, unsigned* __restrict__ bar,
        us* __restrict__ wt0, us* __restrict__ wtb0, us* __restrict__ wta1,
        us* __restrict__ wtb1, us* __restrict__ wta2, us* __restrict__ wtb2,
        float* __restrict__ out) {
    __shared__ __align__(16) unsigned char sm[SM_SIZE];
    int bid = blockIdx.x, tid = threadIdx.x;
    // XCD swizzle: the 4 blocks of a graph are congruent mod 8 -> same XCD (perf hint only)
    int g = (bid & 7) * 8 + ((bid >> 3) & 7);
    int q = bid >> 6;
    unsigned* gc = bar + 544 + g * 32;
    float* pooled = pstat + 12288;
    float p0 = 0.f, p1 = 0.f;

    ph_prep(sm, g, q, bid, tid, esrc, edst, Sb8, wa0, wa1, wa2, wb0, wb1, wb2,
            wt0, wtb0, wta1, wtb1, wta2, wtb2);
    gsync_tree(bar, bid, 1);                        // weight panels ready

    ph_embed(sm, g, q, tid, x, wt0, wa0, gid, ge, he, tT0);
    gbar4(gc, 1);                                   // graph's tT0 ready

    ph_agg(sm, g, q, tid, Sb8, tT0, ba0, pstat + 0, pstat + 2048, bid & 15);
    gsync_tree(bar, bid, 2);                        // BN stats layer 0
    ph_post<0>(sm, g, q, tid, pstat + 0, pstat + 2048, gg0, be0, wtb0, bbias0, wta1, tT1, p0, p1);
    gbar4(gc, 2);

    ph_agg(sm, g, q, tid, Sb8, tT1, ba1, pstat + 4096, pstat + 6144, bid & 15);
    gsync_tree(bar, bid, 3);                        // BN stats layer 1
    ph_post<0>(sm, g, q, tid, pstat + 4096, pstat + 6144, gg1, be1, wtb1, bbias1, wta2, tT2, p0, p1);
    gbar4(gc, 3);

    ph_agg(sm, g, q, tid, Sb8, tT2, ba2, pstat + 8192, pstat + 10240, bid & 15);
    gsync_tree(bar, bid, 4);                        // BN stats layer 2
    ph_post<1>(sm, g, q, tid, pstat + 8192, pstat + 10240, gg2, be2, wtb2, bbias2, nullptr, nullptr, p0, p1);

    {   // per-graph pool: block reduce then coherence-point atomics
        int wave = tid >> 6, lane = tid & 63;
        int wrow = wave >> 2, wc4 = wave & 3;
        float (*red)[4][2][16] = (float(*)[4][2][16])sm;
        p0 += __shfl_xor(p0, 16); p0 += __shfl_xor(p0, 32);
        p1 += __shfl_xor(p1, 16); p1 += __shfl_xor(p1, 32);
        __syncthreads();
        if (lane < 16) { red[wrow][wc4][0][lane] = p0; red[wrow][wc4][1][lane] = p1; }
        __syncthreads();
        if (tid < 128) {
            int wc = tid >> 5, ct = (tid >> 4) & 1, f = tid & 15;
            float s = 0.f;
#pragma unroll
            for (int wr = 0; wr < 4; ++wr) s += red[wr][wc][ct][f];
            atomicAdd(&pooled[g * 128 + tid], s);
        }
    }
    gbar4(gc, 4);

    if (q == 0) {   // head: one block per graph
        float* pl = (float*)sm;
        float* o0 = pl + 128;
        float* o1 = pl + 256;
        __syncthreads();
        if (tid < 128) {
            unsigned uv = __hip_atomic_load((const unsigned*)&pooled[g * 128 + tid],
                                            __ATOMIC_RELAXED, __HIP_MEMORY_SCOPE_AGENT);
            pl[tid] = __uint_as_float(uv);
        }
        __syncthreads();
        if (tid < 128) {
            float a = bfa[tid];
            for (int k = 0; k < 128; ++k) a += pl[k] * wfa[k * 128 + tid];
            float p2 = fmaxf(a, 0.f);
            o0[tid] = p2 * wfb[tid * 2 + 0];
            o1[tid] = p2 * wfb[tid * 2 + 1];
        }
        __syncthreads();
        if (tid == 0) {
            float a0 = bfb[0], a1 = bfb[1];
#pragma unroll
            for (int k = 0; k < 128; ++k) { a0 += o0[k]; a1 += o1[k]; }
            out[g * 2 + 0] = a0;
            out[g * 2 + 1] = a1;
        }
    }
}

// ---------------- launch ----------------

extern "C" void kernel_launch(void* const* d_in, const int* in_sizes, int n_in,
                              void* d_out, int out_size, void* d_ws, size_t ws_size,
                              hipStream_t stream) {
    const float* x   = (const float*)d_in[0];
    const int* ei    = (const int*)d_in[1];
    const int* gid   = (const int*)d_in[3];
    const float* ge  = (const float*)d_in[4];
    const float* he  = (const float*)d_in[5];
    float* out = (float*)d_out;

    char* ws = (char*)d_ws;
    size_t o = 0;
    auto alloc = [&](size_t bytes) { char* p = ws + o; o += (bytes + 255) & ~(size_t)255; return p; };
    size_t tbytes = (size_t)128 * N_NODES * 2;                 // 6553600
    us* tT0 = (us*)alloc(tbytes);
    us* tT1 = (us*)alloc(tbytes);
    us* tT2 = (us*)alloc(tbytes);
    unsigned char* Sb8 = (unsigned char*)alloc((size_t)NB * 448 * 448);   // u8 slab, 12.8 MB
    float* pstat = (float*)alloc(20480 * 4);                   // 81920
    unsigned* bar = (unsigned*)alloc(12288);                   // contiguous after pstat
    us* wt0  = (us*)alloc(128 * 448 * 2);
    us* wtb0 = (us*)alloc(128 * 128 * 2);
    us* wta1 = (us*)alloc(128 * 128 * 2);
    us* wtb1 = (us*)alloc(128 * 128 * 2);
    us* wta2 = (us*)alloc(128 * 128 * 2);
    us* wtb2 = (us*)alloc(128 * 128 * 2);
    (void)ws_size; (void)in_sizes; (void)n_in; (void)out_size;

    // zero stats + barriers in one memset (pstat and bar are contiguous)
    hipMemsetAsync(pstat, 0, 81920 + 12288, stream);

    persist_all<<<NBLK, 1024, 0, stream>>>(
        x, ei, ei + NE, gid, ge, he,
        (const float*)d_in[6],  (const float*)d_in[7],  (const float*)d_in[8],
        (const float*)d_in[9],  (const float*)d_in[10], (const float*)d_in[11],
        (const float*)d_in[12], (const float*)d_in[13], (const float*)d_in[14],
        (const float*)d_in[15], (const float*)d_in[16], (const float*)d_in[17],
        (const float*)d_in[18], (const float*)d_in[19], (const float*)d_in[20],
        (const float*)d_in[21], (const float*)d_in[22], (const float*)d_in[23],
        (const float*)d_in[24], (const float*)d_in[25],
        (const float*)d_in[26], (const float*)d_in[27],
        tT0, tT1, tT2, Sb8, pstat, bar,
        wt0, wtb0, wta1, wtb1, wta2, wtb2,
        out);
}

// Round 11
// 213.201 us; speedup vs baseline: 1.0789x; 1.0789x over previous
//
#include <hip/hip_runtime.h>

#define N_NODES 25600
#define F_IN 400
#define NE 512000
#define NB 64
#define NPG 400
#define EPG 8000
#define BN_EPS 1e-5f
#define NBLK 256

#define A4OFF 129024            // persistent LDS u4 A-slab (128 rows x 232 B = 29696)
#define SM_SIZE 158720

typedef __attribute__((ext_vector_type(8))) short short8;
typedef __attribute__((ext_vector_type(4))) float floatx4;
typedef unsigned short us;
typedef unsigned long long u64;

__device__ __forceinline__ unsigned short f2bf(float f) {
    unsigned int u = __float_as_uint(f);
    u += 0x7FFF + ((u >> 16) & 1);   // RNE
    return (unsigned short)(u >> 16);
}
__device__ __forceinline__ float bf2f(unsigned short s) {
    return __uint_as_float((unsigned int)s << 16);
}
// packed f32x2 -> bf16x2 (RNE), lo in low half
__device__ __forceinline__ unsigned cvtpk(float lo, float hi) {
    unsigned r;
    asm("v_cvt_pk_bf16_f32 %0, %1, %2" : "=v"(r) : "v"(lo), "v"(hi));
    return r;
}
// agent-scope (coherence-point) store: lands at L3, bypassing the writer's non-coherent L2.
__device__ __forceinline__ void ast64(void* p, u64 v) {
    __hip_atomic_store((u64*)p, v, __ATOMIC_RELAXED, __HIP_MEMORY_SCOPE_AGENT);
}
__device__ __forceinline__ u64 pk4(unsigned short a, unsigned short b, unsigned short c, unsigned short d) {
    return (u64)a | ((u64)b << 16) | ((u64)c << 32) | ((u64)d << 48);
}

// ---- hierarchical grid barrier: 16 leaves x 16 blocks + root ----
__device__ __forceinline__ void gsync_tree(unsigned* bar, int bid, int phase) {
    __syncthreads();                       // drains vmcnt: prior stores/atomics complete
    if (threadIdx.x == 0) {
        unsigned* leaf = bar + 32 + (bid >> 4) * 32;        // 128B-spaced lines
        unsigned v = __hip_atomic_fetch_add(leaf, 1u, __ATOMIC_RELAXED, __HIP_MEMORY_SCOPE_AGENT);
        if (v == (unsigned)(phase * 16 - 1))
            __hip_atomic_fetch_add(bar, 1u, __ATOMIC_RELAXED, __HIP_MEMORY_SCOPE_AGENT);
        while (__hip_atomic_load(bar, __ATOMIC_RELAXED, __HIP_MEMORY_SCOPE_AGENT) < (unsigned)(phase * 16))
            __builtin_amdgcn_s_sleep(8);
        asm volatile("" ::: "memory");
    }
    __syncthreads();
}

// ---- per-graph micro-barrier: only the 4 blocks of one graph ----
__device__ __forceinline__ void gbar4(unsigned* gc, int stage) {
    __syncthreads();
    if (threadIdx.x == 0) {
        __hip_atomic_fetch_add(gc, 1u, __ATOMIC_RELAXED, __HIP_MEMORY_SCOPE_AGENT);
        while (__hip_atomic_load(gc, __ATOMIC_RELAXED, __HIP_MEMORY_SCOPE_AGENT) < (unsigned)(stage * 4))
            __builtin_amdgcn_s_sleep(8);
        asm volatile("" ::: "memory");
    }
    __syncthreads();
}

// LDS plan (158720 B static, 1 block/CU):
//  prep : cnt 44800 @0
//  embed: Bf[128][456] @0 (116736) | As[128][72] @116736 (18432) | Wex @135168 (2048)
//  A4   : u4 slab @129024 (29696) — staged once after embed, persists through all 3 agg layers
//  agg  : Bf @0 ; epilogue zl[128][136] @0 ; rs @116736 / rq @118784  (all < A4OFF)
//  post : zl @0 | coefs @34816 | Bw[128][136] @35840 (ends 105472)
//  tail : red @0 ; head pl/o0/o1 @0

// ---------------- prep: u4 adjacency slab (block-private) + balanced weight-panel jobs ----------------

__device__ __forceinline__ void ph_prep(unsigned char* sm, int g, int q, int bid, int tid,
        const int* __restrict__ src, const int* __restrict__ dst, unsigned char* __restrict__ Sb4,
        const float* __restrict__ wa0, const float* __restrict__ wa1, const float* __restrict__ wa2,
        const float* __restrict__ wb0, const float* __restrict__ wb1, const float* __restrict__ wb2,
        us* __restrict__ wt0, us* __restrict__ wtb0, us* __restrict__ wta1,
        us* __restrict__ wtb1, us* __restrict__ wta2, us* __restrict__ wtb2) {
    int r0 = q * 112;
    int* cnt = (int*)sm;                      // 112*400 u8 counts packed in ints
    for (int i = tid; i < 11200; i += 1024) cnt[i] = 0;
    __syncthreads();
    int ebase = g * EPG, nbase = g * NPG;
    for (int e = tid; e < EPG; e += 1024) {
        int d = dst[ebase + e] - nbase;
        int dr = d - r0;
        if ((unsigned)dr < 112u) {
            int s = src[ebase + e] - nbase;
            int idx = dr * NPG + s;
            atomicAdd(&cnt[idx >> 2], (int)(1u << ((idx & 3) * 8)));
        }
    }
    __syncthreads();
    const unsigned char* cb = (const unsigned char*)cnt;
    // pack 8 cells -> u32 nibbles; row stride 224 B in global (56 u32/row)
    for (int i = tid; i < 112 * 56; i += 1024) {
        int rr = i / 56, c8 = (i % 56) * 8;
        int R = r0 + rr;
        unsigned pk = 0;
#pragma unroll
        for (int j = 0; j < 8; ++j) {
            int c = c8 + j;
            unsigned v = (R < NPG && c < NPG) ? (unsigned)cb[rr * NPG + c] + (c == R ? 1u : 0u) : 0u;
            pk |= (v & 15u) << (4 * j);
        }
        *(unsigned*)&Sb4[(size_t)g * 100352 + (size_t)R * 224 + (c8 >> 1)] = pk;   // block-private
    }
    // balanced one-shot jobs: 34816 u64 slots / 256 blocks = 136 each
    if (tid < 136) {
        int idx = bid * 136 + tid;
        if (idx < 14336) {                   // wt0: [n=128][k=448] bf16, zero-padded K
            int n = idx / 112, k0 = (idx % 112) * 4;
            unsigned short o[4];
#pragma unroll
            for (int j = 0; j < 4; ++j) {
                int k = k0 + j;
                o[j] = (k < 400) ? f2bf(wa0[(size_t)k * 128 + n]) : (unsigned short)0;
            }
            ast64(&wt0[(size_t)n * 448 + k0], pk4(o[0], o[1], o[2], o[3]));
        } else {                             // 5 x [n=128][k=128] transposes
            int r2 = idx - 14336;            // 0..20479
            int m = r2 >> 12, q2 = r2 & 4095;
            int n = q2 >> 5, k0 = (q2 & 31) * 4;
            const float* smat = (m == 0) ? wb0 : (m == 1) ? wa1 : (m == 2) ? wb1 : (m == 3) ? wa2 : wb2;
            us* dmat = (m == 0) ? wtb0 : (m == 1) ? wta1 : (m == 2) ? wtb1 : (m == 3) ? wta2 : wtb2;
            unsigned short o[4];
#pragma unroll
            for (int j = 0; j < 4; ++j) o[j] = f2bf(smat[(size_t)(k0 + j) * 128 + n]);
            ast64(&dmat[(size_t)n * 128 + k0], pk4(o[0], o[1], o[2], o[3]));
        }
    }
}

// ---------------- embed: tT0 = ([x | ge | he] @ W0a)^T ----------------

__device__ __forceinline__ void ph_embed(unsigned char* sm, int g, int q, int tid,
        const float* __restrict__ x, const us* __restrict__ wt0, const float* __restrict__ wa0,
        const int* __restrict__ gid, const float* __restrict__ ge, const float* __restrict__ he,
        us* __restrict__ tT0) {
    us (*Bf)[456] = (us(*)[456])sm;
    us (*As)[72] = (us(*)[72])(sm + 116736);
    float (*Wex)[128] = (float(*)[128])(sm + 135168);
    int nb = g * NPG + q * 100;
    int wave = tid >> 6, lane = tid & 63;
    int wrow = wave >> 2, wc4 = wave & 3;
    int fm = lane & 15, quad = lane >> 4;

    // stage full W0^T panel: issue ALL loads, then all LDS writes (7x MLP)
    {
        short8 tp[7];
#pragma unroll
        for (int j = 0; j < 7; ++j) {
            int i = tid + j * 1024;
            int col = i / 56, kq = (i - col * 56) * 8;
            tp[j] = *(const short8*)(wt0 + (size_t)col * 448 + kq);
        }
#pragma unroll
        for (int j = 0; j < 7; ++j) {
            int i = tid + j * 1024;
            int col = i / 56, kq = (i - col * 56) * 8;
            *(short8*)&Bf[col][kq] = tp[j];
        }
    }
    for (int i = tid; i < 512; i += 1024)
        Wex[i >> 7][i & 127] = wa0[(size_t)(400 + (i >> 7)) * 128 + (i & 127)];

    floatx4 acc[2][2];
#pragma unroll
    for (int rt = 0; rt < 2; ++rt)
#pragma unroll
        for (int ct = 0; ct < 2; ++ct) acc[rt][ct] = (floatx4){0.f, 0.f, 0.f, 0.f};

    const int rA = tid >> 3, kcA = (tid & 7) * 8;
    float v[8];
    auto loadK = [&](int ks) {
        int kg = ks * 64 + kcA;
        if (rA < 100) {
            const float* ar = x + (size_t)(nb + rA) * F_IN;
            if (kg + 7 < 400) {
                float4 a = *(const float4*)(ar + kg);
                float4 b = *(const float4*)(ar + kg + 4);
                v[0] = a.x; v[1] = a.y; v[2] = a.z; v[3] = a.w;
                v[4] = b.x; v[5] = b.y; v[6] = b.z; v[7] = b.w;
            } else {
#pragma unroll
                for (int j = 0; j < 8; ++j) v[j] = (kg + j < 400) ? ar[kg + j] : 0.f;
            }
        } else {
#pragma unroll
            for (int j = 0; j < 8; ++j) v[j] = 0.f;
        }
    };

    loadK(0);
    for (int ks = 0; ks < 7; ++ks) {
        {
            union { unsigned w[4]; short8 s; } u;
            u.w[0] = cvtpk(v[0], v[1]);
            u.w[1] = cvtpk(v[2], v[3]);
            u.w[2] = cvtpk(v[4], v[5]);
            u.w[3] = cvtpk(v[6], v[7]);
            *(short8*)&As[rA][kcA] = u.s;
        }
        __syncthreads();            // first iter also covers Bf/Wex staging
        if (ks + 1 < 7) loadK(ks + 1);
#pragma unroll
        for (int k0l = 0; k0l < 64; k0l += 32) {
            short8 af[2], bf[2];
#pragma unroll
            for (int rt = 0; rt < 2; ++rt)
                af[rt] = *(const short8*)&As[wrow * 32 + rt * 16 + fm][k0l + quad * 8];
#pragma unroll
            for (int ct = 0; ct < 2; ++ct)
                bf[ct] = *(const short8*)&Bf[wc4 * 32 + ct * 16 + fm][ks * 64 + k0l + quad * 8];
#pragma unroll
            for (int rt = 0; rt < 2; ++rt)
#pragma unroll
                for (int ct = 0; ct < 2; ++ct)
                    acc[rt][ct] = __builtin_amdgcn_mfma_f32_16x16x32_bf16(
                        af[rt], bf[ct], acc[rt][ct], 0, 0, 0);
        }
        __syncthreads();
    }

#pragma unroll
    for (int rt = 0; rt < 2; ++rt)
#pragma unroll
        for (int ct = 0; ct < 2; ++ct) {
            int col = wc4 * 32 + ct * 16 + fm;
            int rl0 = wrow * 32 + rt * 16 + quad * 4;
            if (rl0 < 100) {
                float vv[4];
#pragma unroll
                for (int r = 0; r < 4; ++r) {
                    int row = nb + rl0 + r;
                    int gv = gid[row];
                    vv[r] = acc[rt][ct][r]
                          + ge[gv * 2] * Wex[0][col] + ge[gv * 2 + 1] * Wex[1][col]
                          + he[(row & 1) * 2] * Wex[2][col] + he[(row & 1) * 2 + 1] * Wex[3][col];
                }
                unsigned wlo = cvtpk(vv[0], vv[1]), whi = cvtpk(vv[2], vv[3]);
                ast64(&tT0[(size_t)col * N_NODES + nb + rl0], (u64)wlo | ((u64)whi << 32));
            }
        }
}

// ---------------- agg: z = (S+I)@t + ba ; A from persistent LDS u4 slab (fast unpack) ----------------

__device__ __forceinline__ void ph_agg(unsigned char* sm, int g, int q, int tid,
        const us* __restrict__ tTr, const float* __restrict__ ba,
        float* __restrict__ psum, float* __restrict__ psq, int bucket) {
    us (*Bf)[456] = (us(*)[456])sm;
    us (*zl)[136] = (us(*)[136])sm;
    float (*rs)[4][2][16] = (float(*)[4][2][16])(sm + 116736);
    float (*rq)[4][2][16] = (float(*)[4][2][16])(sm + 118784);
    const unsigned char* A4 = sm + A4OFF;
    int wave = tid >> 6, lane = tid & 63;
    int wrow = wave >> 2, wc4 = wave & 3;
    int fm = lane & 15, quad = lane >> 4;
    int node0 = g * NPG;

    // stage tT panel: ALL loads first (7x MLP), then LDS writes; k>=400 literal zeros
    {
        short8 tp[7];
        const short8 z8 = {0, 0, 0, 0, 0, 0, 0, 0};
#pragma unroll
        for (int j = 0; j < 7; ++j) {
            int i = tid + j * 1024;
            int col = i / 56, kq = (i - col * 56) * 8;
            tp[j] = (kq < 400) ? *(const short8*)(tTr + (size_t)col * N_NODES + node0 + kq) : z8;
        }
#pragma unroll
        for (int j = 0; j < 7; ++j) {
            int i = tid + j * 1024;
            int col = i / 56, kq = (i - col * 56) * 8;
            *(short8*)&Bf[col][kq] = tp[j];
        }
    }
    __syncthreads();

    floatx4 acc[2][2];
#pragma unroll
    for (int rt = 0; rt < 2; ++rt)
#pragma unroll
        for (int ct = 0; ct < 2; ++ct) acc[rt][ct] = (floatx4){0.f, 0.f, 0.f, 0.f};

#pragma unroll
    for (int ks = 0; ks < 7; ++ks) {
#pragma unroll
        for (int k0l = 0; k0l < 64; k0l += 32) {
            short8 af[2], bf[2];
#pragma unroll
            for (int rt = 0; rt < 2; ++rt) {
                int row = wrow * 32 + rt * 16 + fm;
                unsigned w = *(const unsigned*)(A4 + row * 232 + ks * 32 + (k0l >> 1) + quad * 4);
                unsigned e = w & 0x0F0F0F0Fu;          // nibbles 0,2,4,6 as bytes
                unsigned o = (w >> 4) & 0x0F0F0F0Fu;   // nibbles 1,3,5,7
                float f0 = (float)(e & 255u),         f1 = (float)(o & 255u);
                float f2 = (float)((e >> 8) & 255u),  f3 = (float)((o >> 8) & 255u);
                float f4 = (float)((e >> 16) & 255u), f5 = (float)((o >> 16) & 255u);
                float f6 = (float)(e >> 24),          f7 = (float)(o >> 24);
                union { unsigned w4[4]; short8 s; } u;
                // bf16 truncation exact for ints <= 15
                u.w4[0] = __builtin_amdgcn_perm(__float_as_uint(f1), __float_as_uint(f0), 0x07060302u);
                u.w4[1] = __builtin_amdgcn_perm(__float_as_uint(f3), __float_as_uint(f2), 0x07060302u);
                u.w4[2] = __builtin_amdgcn_perm(__float_as_uint(f5), __float_as_uint(f4), 0x07060302u);
                u.w4[3] = __builtin_amdgcn_perm(__float_as_uint(f7), __float_as_uint(f6), 0x07060302u);
                af[rt] = u.s;
            }
#pragma unroll
            for (int ct = 0; ct < 2; ++ct)
                bf[ct] = *(const short8*)&Bf[wc4 * 32 + ct * 16 + fm][ks * 64 + k0l + quad * 8];
#pragma unroll
            for (int rt = 0; rt < 2; ++rt)
#pragma unroll
                for (int ct = 0; ct < 2; ++ct)
                    acc[rt][ct] = __builtin_amdgcn_mfma_f32_16x16x32_bf16(
                        af[rt], bf[ct], acc[rt][ct], 0, 0, 0);
        }
    }
    __syncthreads();   // B panel dead; zl overlays it

    int nrows = (q < 3) ? 112 : 64;
    float sc[2] = {0.f, 0.f}, sq2[2] = {0.f, 0.f};
#pragma unroll
    for (int rt = 0; rt < 2; ++rt)
#pragma unroll
        for (int ct = 0; ct < 2; ++ct) {
            int col = wc4 * 32 + ct * 16 + fm;
            int rl0 = wrow * 32 + rt * 16 + quad * 4;
            if (rl0 < nrows) {
                float bv = ba[col];
                float vv[4];
#pragma unroll
                for (int r = 0; r < 4; ++r) {
                    vv[r] = acc[rt][ct][r] + bv;
                    sc[ct] += vv[r];
                    sq2[ct] += vv[r] * vv[r];
                }
                unsigned w01 = cvtpk(vv[0], vv[1]), w23 = cvtpk(vv[2], vv[3]);
                zl[rl0 + 0][col] = (us)(w01 & 0xffffu);
                zl[rl0 + 1][col] = (us)(w01 >> 16);
                zl[rl0 + 2][col] = (us)(w23 & 0xffffu);
                zl[rl0 + 3][col] = (us)(w23 >> 16);
            }
        }
#pragma unroll
    for (int ct = 0; ct < 2; ++ct) {
        sc[ct] += __shfl_xor(sc[ct], 16);
        sc[ct] += __shfl_xor(sc[ct], 32);
        sq2[ct] += __shfl_xor(sq2[ct], 16);
        sq2[ct] += __shfl_xor(sq2[ct], 32);
    }
    if (lane < 16) {
#pragma unroll
        for (int ct = 0; ct < 2; ++ct) { rs[wrow][wc4][ct][lane] = sc[ct]; rq[wrow][wc4][ct][lane] = sq2[ct]; }
    }
    __syncthreads();
    if (tid < 128) {
        int wc = tid >> 5, ct = (tid >> 4) & 1, f = tid & 15;
        float S = 0.f, Q = 0.f;
#pragma unroll
        for (int wr = 0; wr < 4; ++wr) { S += rs[wr][wc][ct][f]; Q += rq[wr][wc][ct][f]; }
        atomicAdd(&psum[bucket * 128 + tid], S);
        atomicAdd(&psq[bucket * 128 + tid], Q);
    }
}

// ---------------- post: BN + h=relu(relu(affine(z))@wb+bb) [+ t'=h@wa_next | pool] ----------------

template <int FINAL>
__device__ __forceinline__ void ph_post(unsigned char* sm, int g, int q, int tid,
        const float* __restrict__ psum, const float* __restrict__ psq,
        const float* __restrict__ gamma, const float* __restrict__ beta,
        const us* __restrict__ wtbP, const float* __restrict__ bb,
        const us* __restrict__ wanP, us* __restrict__ tTw, float& p0, float& p1) {
    us (*zl)[136] = (us(*)[136])sm;
    float* coefs = (float*)(sm + 34816);
    us (*Bw)[136] = (us(*)[136])(sm + 35840);
    int wave = tid >> 6, lane = tid & 63;
    int wrow = wave >> 2, wc4 = wave & 3;
    int fm = lane & 15, quad = lane >> 4;
    int nrows = (q < 3) ? 112 : 64;
    int nb = g * NPG + q * 112;

    // prefetch both weight panels (w2 held in registers across GEMM1)
    short8 w1[2], w2[2];
#pragma unroll
    for (int j = 0; j < 2; ++j) {
        int i = tid + j * 1024;
        int col = i >> 4, kq = (i & 15) * 8;
        w1[j] = *(const short8*)(wtbP + (size_t)col * 128 + kq);
        if (!FINAL) w2[j] = *(const short8*)(wanP + (size_t)col * 128 + kq);
    }

    if (tid < 128) {
        float S = 0.f, Q = 0.f;
#pragma unroll
        for (int b = 0; b < 16; ++b) {
            S += __hip_atomic_load(&psum[b * 128 + tid], __ATOMIC_RELAXED, __HIP_MEMORY_SCOPE_AGENT);
            Q += __hip_atomic_load(&psq[b * 128 + tid], __ATOMIC_RELAXED, __HIP_MEMORY_SCOPE_AGENT);
        }
        float invn = 1.0f / (float)N_NODES;
        float mu = S * invn;
        float var = Q * invn - mu * mu;
        float a = gamma[tid] * rsqrtf(var + BN_EPS);
        coefs[tid] = a;
        coefs[128 + tid] = beta[tid] - a * mu;
    }
#pragma unroll
    for (int j = 0; j < 2; ++j) {
        int i = tid + j * 1024;
        int col = i >> 4, kq = (i & 15) * 8;
        *(short8*)&Bw[col][kq] = w1[j];
    }
    __syncthreads();                 // coefs + Bw(wb^T) ready
    // affine + relu in place, pairwise
    for (int i = tid; i < 8192; i += 1024) {
        int rl = i >> 6, c2 = i & 63;
        unsigned* zw = (unsigned*)&zl[rl][0];
        unsigned w = zw[c2];
        int col = c2 * 2;
        float lo = fmaxf(coefs[col] * bf2f((us)(w & 0xffff)) + coefs[128 + col], 0.f);
        float hi = fmaxf(coefs[col + 1] * bf2f((us)(w >> 16)) + coefs[129 + col], 0.f);
        zw[c2] = cvtpk(lo, hi);
    }
    __syncthreads();                 // zl ready

    floatx4 acc[2][2];
#pragma unroll
    for (int rt = 0; rt < 2; ++rt)
#pragma unroll
        for (int ct = 0; ct < 2; ++ct) acc[rt][ct] = (floatx4){0.f, 0.f, 0.f, 0.f};

#pragma unroll
    for (int ks = 0; ks < 2; ++ks)
#pragma unroll
        for (int k0l = 0; k0l < 64; k0l += 32) {
            short8 af[2], bf[2];
#pragma unroll
            for (int rt = 0; rt < 2; ++rt)
                af[rt] = *(const short8*)&zl[wrow * 32 + rt * 16 + fm][ks * 64 + k0l + quad * 8];
#pragma unroll
            for (int ct = 0; ct < 2; ++ct)
                bf[ct] = *(const short8*)&Bw[wc4 * 32 + ct * 16 + fm][ks * 64 + k0l + quad * 8];
#pragma unroll
            for (int rt = 0; rt < 2; ++rt)
#pragma unroll
                for (int ct = 0; ct < 2; ++ct)
                    acc[rt][ct] = __builtin_amdgcn_mfma_f32_16x16x32_bf16(
                        af[rt], bf[ct], acc[rt][ct], 0, 0, 0);
        }

    if (FINAL) {
#pragma unroll
        for (int rt = 0; rt < 2; ++rt)
#pragma unroll
            for (int ct = 0; ct < 2; ++ct) {
                int col = wc4 * 32 + ct * 16 + fm;
                int rl0 = wrow * 32 + rt * 16 + quad * 4;
                if (rl0 < nrows) {
                    float bv = bb[col];
                    float s = 0.f;
#pragma unroll
                    for (int r = 0; r < 4; ++r) s += fmaxf(acc[rt][ct][r] + bv, 0.f);
                    if (ct == 0) p0 += s; else p1 += s;
                }
            }
        return;
    }

    __syncthreads();                 // all GEMM1 reads of zl and Bw done
    // h -> zl (in place); Bw <- wa_next^T (held registers)
#pragma unroll
    for (int rt = 0; rt < 2; ++rt)
#pragma unroll
        for (int ct = 0; ct < 2; ++ct) {
            int col = wc4 * 32 + ct * 16 + fm;
            float bv = bb[col];
            int rl0 = wrow * 32 + rt * 16 + quad * 4;
            float h0 = fmaxf(acc[rt][ct][0] + bv, 0.f), h1 = fmaxf(acc[rt][ct][1] + bv, 0.f);
            float h2 = fmaxf(acc[rt][ct][2] + bv, 0.f), h3 = fmaxf(acc[rt][ct][3] + bv, 0.f);
            unsigned w01 = cvtpk(h0, h1), w23 = cvtpk(h2, h3);
            zl[rl0 + 0][col] = (us)(w01 & 0xffffu);
            zl[rl0 + 1][col] = (us)(w01 >> 16);
            zl[rl0 + 2][col] = (us)(w23 & 0xffffu);
            zl[rl0 + 3][col] = (us)(w23 >> 16);
        }
#pragma unroll
    for (int j = 0; j < 2; ++j) {
        int i = tid + j * 1024;
        int col = i >> 4, kq = (i & 15) * 8;
        *(short8*)&Bw[col][kq] = w2[j];
    }
    __syncthreads();

#pragma unroll
    for (int rt = 0; rt < 2; ++rt)
#pragma unroll
        for (int ct = 0; ct < 2; ++ct) acc[rt][ct] = (floatx4){0.f, 0.f, 0.f, 0.f};

#pragma unroll
    for (int ks = 0; ks < 2; ++ks)
#pragma unroll
        for (int k0l = 0; k0l < 64; k0l += 32) {
            short8 af[2], bf[2];
#pragma unroll
            for (int rt = 0; rt < 2; ++rt)
                af[rt] = *(const short8*)&zl[wrow * 32 + rt * 16 + fm][ks * 64 + k0l + quad * 8];
#pragma unroll
            for (int ct = 0; ct < 2; ++ct)
                bf[ct] = *(const short8*)&Bw[wc4 * 32 + ct * 16 + fm][ks * 64 + k0l + quad * 8];
#pragma unroll
            for (int rt = 0; rt < 2; ++rt)
#pragma unroll
                for (int ct = 0; ct < 2; ++ct)
                    acc[rt][ct] = __builtin_amdgcn_mfma_f32_16x16x32_bf16(
                        af[rt], bf[ct], acc[rt][ct], 0, 0, 0);
        }

#pragma unroll
    for (int rt = 0; rt < 2; ++rt)
#pragma unroll
        for (int ct = 0; ct < 2; ++ct) {
            int col = wc4 * 32 + ct * 16 + fm;
            int rl0 = wrow * 32 + rt * 16 + quad * 4;
            if (rl0 < nrows) {
                unsigned wlo = cvtpk(acc[rt][ct][0], acc[rt][ct][1]);
                unsigned whi = cvtpk(acc[rt][ct][2], acc[rt][ct][3]);
                ast64(&tTw[(size_t)col * N_NODES + nb + rl0], (u64)wlo | ((u64)whi << 32));
            }
        }
}

// ---------------- the single persistent kernel ----------------

__global__ __launch_bounds__(1024, 4) void persist_all(
        const float* __restrict__ x, const int* __restrict__ esrc, const int* __restrict__ edst,
        const int* __restrict__ gid, const float* __restrict__ ge, const float* __restrict__ he,
        const float* __restrict__ wa0, const float* __restrict__ ba0, const float* __restrict__ gg0,
        const float* __restrict__ be0, const float* __restrict__ wb0, const float* __restrict__ bbias0,
        const float* __restrict__ wa1, const float* __restrict__ ba1, const float* __restrict__ gg1,
        const float* __restrict__ be1, const float* __restrict__ wb1, const float* __restrict__ bbias1,
        const float* __restrict__ wa2, const float* __restrict__ ba2, const float* __restrict__ gg2,
        const float* __restrict__ be2, const float* __restrict__ wb2, const float* __restrict__ bbias2,
        const float* __restrict__ wfa, const float* __restrict__ bfa,
        const float* __restrict__ wfb, const float* __restrict__ bfb,
        us* __restrict__ tT0, us* __restrict__ tT1, us* __restrict__ tT2,
        unsigned char* __restrict__ Sb4, float* __restrict__ pstat, unsigned* __restrict__ bar,
        us* __restrict__ wt0, us* __restrict__ wtb0, us* __restrict__ wta1,
        us* __restrict__ wtb1, us* __restrict__ wta2, us* __restrict__ wtb2,
        float* __restrict__ out) {
    __shared__ __align__(16) unsigned char sm[SM_SIZE];
    int bid = blockIdx.x, tid = threadIdx.x;
    // XCD swizzle: the 4 blocks of a graph are congruent mod 8 -> same XCD (perf hint only)
    int g = (bid & 7) * 8 + ((bid >> 3) & 7);
    int q = bid >> 6;
    unsigned* gc = bar + 544 + g * 32;
    float* pooled = pstat + 12288;
    float p0 = 0.f, p1 = 0.f;

    ph_prep(sm, g, q, bid, tid, esrc, edst, Sb4, wa0, wa1, wa2, wb0, wb1, wb2,
            wt0, wtb0, wta1, wtb1, wta2, wtb2);
    gsync_tree(bar, bid, 1);                        // weight panels ready

    ph_embed(sm, g, q, tid, x, wt0, wa0, gid, ge, he, tT0);

    // issue persistent A-slab loads (block-private, ready since prep) to hide under the barrier
    u64 aP4[4];
    {
        const u64* gs = (const u64*)(Sb4 + (size_t)g * 100352 + (size_t)q * 25088);
#pragma unroll
        for (int j = 0; j < 4; ++j) {
            int i = tid + j * 1024;
            aP4[j] = (i < 3136) ? gs[i] : 0ull;
        }
    }
    gbar4(gc, 1);                                   // graph's tT0 ready (also syncs embed LDS use)
    {
#pragma unroll
        for (int j = 0; j < 4; ++j) {
            int i = tid + j * 1024;
            if (i < 3584) {                         // rows 112..127 zero
                int rr = i / 28, c = i - rr * 28;
                *(u64*)(sm + A4OFF + rr * 232 + c * 8) = aP4[j];
            }
        }
    }   // ph_agg's staging __syncthreads publishes A4 before first use

    ph_agg(sm, g, q, tid, tT0, ba0, pstat + 0, pstat + 2048, bid & 15);
    gsync_tree(bar, bid, 2);                        // BN stats layer 0
    ph_post<0>(sm, g, q, tid, pstat + 0, pstat + 2048, gg0, be0, wtb0, bbias0, wta1, tT1, p0, p1);
    gbar4(gc, 2);

    ph_agg(sm, g, q, tid, tT1, ba1, pstat + 4096, pstat + 6144, bid & 15);
    gsync_tree(bar, bid, 3);                        // BN stats layer 1
    ph_post<0>(sm, g, q, tid, pstat + 4096, pstat + 6144, gg1, be1, wtb1, bbias1, wta2, tT2, p0, p1);
    gbar4(gc, 3);

    ph_agg(sm, g, q, tid, tT2, ba2, pstat + 8192, pstat + 10240, bid & 15);
    gsync_tree(bar, bid, 4);                        // BN stats layer 2
    ph_post<1>(sm, g, q, tid, pstat + 8192, pstat + 10240, gg2, be2, wtb2, bbias2, nullptr, nullptr, p0, p1);

    {   // per-graph pool: block reduce then coherence-point atomics
        int wave = tid >> 6, lane = tid & 63;
        int wrow = wave >> 2, wc4 = wave & 3;
        float (*red)[4][2][16] = (float(*)[4][2][16])sm;
        p0 += __shfl_xor(p0, 16); p0 += __shfl_xor(p0, 32);
        p1 += __shfl_xor(p1, 16); p1 += __shfl_xor(p1, 32);
        __syncthreads();
        if (lane < 16) { red[wrow][wc4][0][lane] = p0; red[wrow][wc4][1][lane] = p1; }
        __syncthreads();
        if (tid < 128) {
            int wc = tid >> 5, ct = (tid >> 4) & 1, f = tid & 15;
            float s = 0.f;
#pragma unroll
            for (int wr = 0; wr < 4; ++wr) s += red[wr][wc][ct][f];
            atomicAdd(&pooled[g * 128 + tid], s);
        }
    }
    gbar4(gc, 4);

    if (q == 0) {   // head: one block per graph
        float* pl = (float*)sm;
        float* o0 = pl + 128;
        float* o1 = pl + 256;
        __syncthreads();
        if (tid < 128) {
            unsigned uv = __hip_atomic_load((const unsigned*)&pooled[g * 128 + tid],
                                            __ATOMIC_RELAXED, __HIP_MEMORY_SCOPE_AGENT);
            pl[tid] = __uint_as_float(uv);
        }
        __syncthreads();
        if (tid < 128) {
            float a = bfa[tid];
            for (int k = 0; k < 128; ++k) a += pl[k] * wfa[k * 128 + tid];
            float p2 = fmaxf(a, 0.f);
            o0[tid] = p2 * wfb[tid * 2 + 0];
            o1[tid] = p2 * wfb[tid * 2 + 1];
        }
        __syncthreads();
        if (tid == 0) {
            float a0 = bfb[0], a1 = bfb[1];
#pragma unroll
            for (int k = 0; k < 128; ++k) { a0 += o0[k]; a1 += o1[k]; }
            out[g * 2 + 0] = a0;
            out[g * 2 + 1] = a1;
        }
    }
}

// ---------------- launch ----------------

extern "C" void kernel_launch(void* const* d_in, const int* in_sizes, int n_in,
                              void* d_out, int out_size, void* d_ws, size_t ws_size,
                              hipStream_t stream) {
    const float* x   = (const float*)d_in[0];
    const int* ei    = (const int*)d_in[1];
    const int* gid   = (const int*)d_in[3];
    const float* ge  = (const float*)d_in[4];
    const float* he  = (const float*)d_in[5];
    float* out = (float*)d_out;

    char* ws = (char*)d_ws;
    size_t o = 0;
    auto alloc = [&](size_t bytes) { char* p = ws + o; o += (bytes + 255) & ~(size_t)255; return p; };
    size_t tbytes = (size_t)128 * N_NODES * 2;                 // 6553600
    us* tT0 = (us*)alloc(tbytes);
    us* tT1 = (us*)alloc(tbytes);
    us* tT2 = (us*)alloc(tbytes);
    unsigned char* Sb4 = (unsigned char*)alloc((size_t)NB * 100352);   // u4 slab, 6.4 MB
    float* pstat = (float*)alloc(20480 * 4);                   // 81920
    unsigned* bar = (unsigned*)alloc(12288);                   // contiguous after pstat
    us* wt0  = (us*)alloc(128 * 448 * 2);
    us* wtb0 = (us*)alloc(128 * 128 * 2);
    us* wta1 = (us*)alloc(128 * 128 * 2);
    us* wtb1 = (us*)alloc(128 * 128 * 2);
    us* wta2 = (us*)alloc(128 * 128 * 2);
    us* wtb2 = (us*)alloc(128 * 128 * 2);
    (void)ws_size; (void)in_sizes; (void)n_in; (void)out_size;

    // zero stats + barriers in one memset (pstat and bar are contiguous)
    hipMemsetAsync(pstat, 0, 81920 + 12288, stream);

    persist_all<<<NBLK, 1024, 0, stream>>>(
        x, ei, ei + NE, gid, ge, he,
        (const float*)d_in[6],  (const float*)d_in[7],  (const float*)d_in[8],
        (const float*)d_in[9],  (const float*)d_in[10], (const float*)d_in[11],
        (const float*)d_in[12], (const float*)d_in[13], (const float*)d_in[14],
        (const float*)d_in[15], (const float*)d_in[16], (const float*)d_in[17],
        (const float*)d_in[18], (const float*)d_in[19], (const float*)d_in[20],
        (const float*)d_in[21], (const float*)d_in[22], (const float*)d_in[23],
        (const float*)d_in[24], (const float*)d_in[25],
        (const float*)d_in[26], (const float*)d_in[27],
        tT0, tT1, tT2, Sb4, pstat, bar,
        wt0, wtb0, wta1, wtb1, wta2, wtb2,
        out);
}